// Round 1
// baseline (356.910 us; speedup 1.0000x reference)
//
#include <hip/hip_runtime.h>

// Problem constants (from reference)
#define HH 256
#define WW 704
#define BB 8
#define CC 5
#define NXc 200
#define NYc 200
#define NZc 8
#define VV (NZc * NXc * NYc)   // 320000
#define HW (HH * WW)           // 180224

// One thread = 4 consecutive pixels (float4 loads). grid.y = batch.
__global__ __launch_bounds__(256) void fpv_scatter_kernel(
    const float* __restrict__ depth,   // (B,1,H,W)
    const float* __restrict__ sem,     // (B,C,H,W)
    const float* __restrict__ Kmat,    // (B,3,3)
    float* __restrict__ out)           // (B,C,V)
{
    const int b  = blockIdx.y;
    const int t  = blockIdx.x * blockDim.x + threadIdx.x;
    const int p0 = t * 4;
    if (p0 >= HW) return;

    // Per-batch intrinsics (uniform within block -> scalar loads)
    const float fx = Kmat[b * 9 + 0];
    const float fy = Kmat[b * 9 + 4];
    const float cx = Kmat[b * 9 + 2];
    const float cy = Kmat[b * 9 + 5];

    const float4 d4 = *reinterpret_cast<const float4*>(depth + (size_t)b * HW + p0);
    float4 l4[CC];
#pragma unroll
    for (int c = 0; c < CC; ++c)
        l4[c] = *reinterpret_cast<const float4*>(sem + ((size_t)b * CC + c) * HW + p0);

    const float dvals[4] = {d4.x, d4.y, d4.z, d4.w};

#pragma unroll
    for (int j = 0; j < 4; ++j) {
        const int p = p0 + j;
        const int v = p / WW;          // row
        const int u = p - v * WW;      // col

        // --- index math: EXACT op order of the JAX reference ---
        float d = fminf(fmaxf(dvals[j], 1.0f), 50.0f);     // clip(d, dmin, dmax)
        float x_cam = ((float)u - cx) * d / fx;
        float y_cam = ((float)v - cy) * d / fy;
        // z_cam = d
        int xi = (int)((x_cam + 50.0f) / 0.5f);   // (x - XB0)/XBres, trunc toward 0
        int yi = (int)((d     + 50.0f) / 0.5f);   // (z - YB0)/YBres
        int zi = (int)((y_cam +  2.0f) / 1.0f);   // (y - ZB0)/ZBres

        bool valid = (xi >= 0) && (xi < NXc) && (yi >= 0) && (yi < NYc)
                  && (zi >= 0) && (zi < NZc);
        if (!valid) continue;

        // --- softmax over C=5 for this pixel ---
        float lg[CC];
#pragma unroll
        for (int c = 0; c < CC; ++c)
            lg[c] = ((const float*)&l4[c])[j];

        float m = lg[0];
#pragma unroll
        for (int c = 1; c < CC; ++c) m = fmaxf(m, lg[c]);

        float e[CC];
        float s = 0.0f;
#pragma unroll
        for (int c = 0; c < CC; ++c) { e[c] = expf(lg[c] - m); s += e[c]; }

        const int flat = zi * (NXc * NYc) + xi * NYc + yi;
        float* dst = out + (size_t)b * CC * VV + flat;
#pragma unroll
        for (int c = 0; c < CC; ++c)
            atomicAdd(dst + (size_t)c * VV, e[c] / s);
    }
}

extern "C" void kernel_launch(void* const* d_in, const int* in_sizes, int n_in,
                              void* d_out, int out_size, void* d_ws, size_t ws_size,
                              hipStream_t stream) {
    const float* depth = (const float*)d_in[0];
    const float* sem   = (const float*)d_in[1];
    const float* Kmat  = (const float*)d_in[2];
    float* out = (float*)d_out;

    // Harness poisons d_out with 0xAA before every launch -> zero it.
    hipMemsetAsync(out, 0, (size_t)out_size * sizeof(float), stream);

    // HW/4 threads per batch = 45056 -> 176 blocks of 256
    dim3 grid(HW / 4 / 256, BB);
    fpv_scatter_kernel<<<grid, 256, 0, stream>>>(depth, sem, Kmat, out);
}